// Round 1
// baseline (1869.104 us; speedup 1.0000x reference)
//
#include <hip/hip_runtime.h>
#include <math.h>

#define BATCH 32768
#define TOBS  20
#define TPRED 12

typedef _Float16 f16;
typedef _Float16 h2_t __attribute__((ext_vector_type(2)));

// ---------------- d_ws layout (bytes) ----------------
#define OFF_W0   0u          // L0 W_hh pack: 16384 f16 (32 KB)
#define OFF_W1   32768u      // L1 cat [W_ih1;W_hh1] pack: 32768 f16 (64 KB)
#define OFF_WD   98304u      // dec W_hh pack: 16384 f16 (32 KB)
#define OFF_IH0  131072u     // L0 W_ih pack: 512 f32 (2 KB)
#define OFF_IHD  133120u     // dec W_ih pack: 512 f32 (2 KB)
#define OFF_B0   135168u     // folded biases, [jj][s][g] f32 (1 KB each)
#define OFF_B1   136192u
#define OFF_BD   137216u
#define OFF_OW   138240u     // out_w as f16 [d][k]: 128 f16 (256 B)
#define OFF_OB   138496u     // out_b: 2 f32
#define OFF_C0   (1u<<20)    // c-state layer0: [64][BATCH] f32 (8 MB)
#define OFF_C1   ((1u<<20)+(8u<<20))   // c-state layer1/decoder (8 MB)
#define WS_NEED  ((size_t)((1u<<20)+(16u<<20)))

__device__ __forceinline__ h2_t bc16(unsigned u){ return __builtin_bit_cast(h2_t, u); }

__device__ __forceinline__ float frcp(float x){
#if __has_builtin(__builtin_amdgcn_rcpf)
  return __builtin_amdgcn_rcpf(x);
#else
  return 1.0f/x;
#endif
}
__device__ __forceinline__ float fsig(float x){ return frcp(1.0f + __expf(-x)); }
__device__ __forceinline__ float ftanh_(float x){
  float e = __expf(-2.0f*x); return (1.0f - e)*frcp(1.0f + e);
}
__device__ __forceinline__ float fdot2(h2_t a, h2_t b, float c){
#if __has_builtin(__builtin_amdgcn_fdot2)
  return __builtin_amdgcn_fdot2(a, b, c, false);
#else
  return c + (float)a[0]*(float)b[0] + (float)a[1]*(float)b[1];
#endif
}

// ---------------- weight packing ----------------
// big packs: half index = ((jj*KK + kk)*8 + s)*8 + g*2 + kp
//   -> per (jj,kk) a lane (s) reads one uint4 = 4 gates x k-pair, conflict-free.
__global__ void prep_pack(const float* __restrict__ wih0, const float* __restrict__ whh0,
                          const float* __restrict__ bih0, const float* __restrict__ bhh0,
                          const float* __restrict__ wih1, const float* __restrict__ whh1,
                          const float* __restrict__ bih1, const float* __restrict__ bhh1,
                          const float* __restrict__ dwih, const float* __restrict__ dwhh,
                          const float* __restrict__ dbih, const float* __restrict__ dbhh,
                          const float* __restrict__ outw, const float* __restrict__ outb,
                          char* __restrict__ ws)
{
  const int tid = blockIdx.x*blockDim.x + threadIdx.x;
  const int stride = gridDim.x*blockDim.x;
  f16* w0 = (f16*)(ws + OFF_W0);
  f16* w1 = (f16*)(ws + OFF_W1);
  f16* wd = (f16*)(ws + OFF_WD);
  for (int i = tid; i < 16384; i += stride) {
    int kp = i & 1, g = (i>>1)&3, s = (i>>3)&7, kk = (i>>6)&31, jj = i>>11;
    int row = g*64 + s*8 + jj, k = kk*2+kp;
    w0[i] = (f16)whh0[row*64+k];
    wd[i] = (f16)dwhh[row*64+k];
  }
  for (int i = tid; i < 32768; i += stride) {
    int kp = i & 1, g = (i>>1)&3, s = (i>>3)&7, kk = (i>>6)&63, jj = i>>12;
    int row = g*64 + s*8 + jj, k = kk*2+kp;
    w1[i] = (f16)((k < 64) ? wih1[row*64+k] : whh1[row*64 + (k-64)]);
  }
  float* ih0 = (float*)(ws + OFF_IH0);
  float* ihd = (float*)(ws + OFF_IHD);
  for (int i = tid; i < 512; i += stride) {
    int k = i & 1, g = (i>>1)&3, s = (i>>3)&7, jj = i>>6;
    int row = g*64 + s*8 + jj;
    ih0[i] = wih0[row*2+k];
    ihd[i] = dwih[row*2+k];
  }
  float* b0 = (float*)(ws + OFF_B0);
  float* b1 = (float*)(ws + OFF_B1);
  float* bd = (float*)(ws + OFF_BD);
  for (int i = tid; i < 256; i += stride) {
    int g = i&3, s = (i>>2)&7, jj = i>>5;
    int row = g*64 + s*8 + jj;
    b0[i] = bih0[row] + bhh0[row];
    b1[i] = bih1[row] + bhh1[row];
    bd[i] = dbih[row] + dbhh[row];
  }
  f16* ow = (f16*)(ws + OFF_OW);
  for (int i = tid; i < 128; i += stride) ow[i] = (f16)outw[i];
  if (tid < 2) ((float*)(ws + OFF_OB))[tid] = outb[tid];
}

// ---------------- fused LSTM ----------------
// wg = 256 thr (4 waves), 64 elements/wg. lane: s=lane&7 -> j in [s*8,s*8+8),
// m=lane>>3 -> element pair. h-state: packed half2 in VGPRs (2 elems/lane).
// c-state: fp32 in d_ws (L2-resident, prefetched). Cross-lane h exchange via
// wave-private LDS stage rows (stride 72 f16 = 144 B, 16B-aligned, 2-way max).
__global__ __launch_bounds__(256, 2)
void lstm_fused(const float* __restrict__ obs, char* __restrict__ ws, float* __restrict__ out)
{
  __shared__ __align__(16) f16   lw0[16384];   // 32 KB: L0 hh pack / dec hh pack
  __shared__ __align__(16) float lih[512];     // 2 KB: L0 ih pack / dec ih pack
  __shared__ __align__(16) float lb0[256];
  __shared__ __align__(16) float lb1[256];
  __shared__ __align__(16) float lbd[256];
  __shared__ __align__(16) f16   lowv[128];
  __shared__ float lob[2];
  __shared__ __align__(16) f16   stg0[64*72];  // 9 KB
  __shared__ __align__(16) f16   stg1[64*72];  // 9 KB   -> total ~55.3 KB

  const int tid = threadIdx.x;
  {
    const uint4* sp = (const uint4*)(ws + OFF_W0);
    uint4* d = (uint4*)lw0;
    #pragma unroll
    for (int i=0;i<8;i++) d[tid + 256*i] = sp[tid + 256*i];
    if (tid < 128) ((uint4*)lih)[tid] = ((const uint4*)(ws + OFF_IH0))[tid];
    if (tid < 64)  ((uint4*)lb0)[tid] = ((const uint4*)(ws + OFF_B0))[tid];
    if (tid < 64)  ((uint4*)lb1)[tid] = ((const uint4*)(ws + OFF_B1))[tid];
    if (tid < 64)  ((uint4*)lbd)[tid] = ((const uint4*)(ws + OFF_BD))[tid];
    if (tid < 16)  ((uint4*)lowv)[tid] = ((const uint4*)(ws + OFF_OW))[tid];
    if (tid < 2)   lob[tid] = ((const float*)(ws + OFF_OB))[tid];
  }
  __syncthreads();

  const int lane = tid & 63;
  const int wv_  = tid >> 6;
  const int s    = lane & 7;
  const int m    = lane >> 3;
  const int eloc = wv_*16 + m*2;
  const int e0   = blockIdx.x*64 + eloc;

  float* __restrict__ C0 = (float*)(ws + OFF_C0);
  float* __restrict__ C1 = (float*)(ws + OFF_C1);
  const uint4* __restrict__ gw1 = (const uint4*)(ws + OFF_W1);

  h2_t h0[2][32], h1[2][32];
  #pragma unroll
  for (int kk=0;kk<32;kk++){ h0[0][kk]=bc16(0u); h0[1][kk]=bc16(0u); h1[0][kk]=bc16(0u); h1[1][kk]=bc16(0u); }

  for (int t = 0; t < TOBS; ++t) {
    float x0[2], x1[2];
    #pragma unroll
    for (int e=0;e<2;e++){
      const float2 xv = *(const float2*)(obs + ((size_t)(e0+e)*TOBS + t)*2);
      x0[e]=xv.x; x1[e]=xv.y;
    }

    // ===== layer 0 (weights from LDS) =====
    for (int jj = 0; jj < 8; ++jj) {
      const int j = s*8 + jj;
      const float2 cp  = *(const float2*)(C0 + (size_t)j*BATCH + e0);   // prefetch
      const float4 bz  = *(const float4*)(lb0 + (jj*8+s)*4);
      const float4 wxa = *(const float4*)(lih + (jj*8+s)*8);
      const float4 wxb = *(const float4*)(lih + (jj*8+s)*8 + 4);
      float z[4][2];
      #pragma unroll
      for (int e=0;e<2;e++){
        z[0][e] = bz.x + wxa.x*x0[e] + wxa.y*x1[e];
        z[1][e] = bz.y + wxa.z*x0[e] + wxa.w*x1[e];
        z[2][e] = bz.z + wxb.x*x0[e] + wxb.y*x1[e];
        z[3][e] = bz.w + wxb.z*x0[e] + wxb.w*x1[e];
      }
      const uint4* wp = (const uint4*)lw0 + jj*256 + s;
      #pragma unroll
      for (int kk = 0; kk < 32; ++kk) {
        const uint4 wq = wp[kk*8];
        #pragma unroll
        for (int e=0;e<2;e++){
          z[0][e] = fdot2(bc16(wq.x), h0[e][kk], z[0][e]);
          z[1][e] = fdot2(bc16(wq.y), h0[e][kk], z[1][e]);
          z[2][e] = fdot2(bc16(wq.z), h0[e][kk], z[2][e]);
          z[3][e] = fdot2(bc16(wq.w), h0[e][kk], z[3][e]);
        }
      }
      const float cold[2] = {cp.x, cp.y};
      float cnv[2];
      #pragma unroll
      for (int e=0;e<2;e++){
        const float ig = fsig(z[0][e]);
        const float fg = fsig(z[1][e]);
        const float gg = ftanh_(z[2][e]);
        const float og = fsig(z[3][e]);
        const float cn = fg*cold[e] + ig*gg;
        const float hn = og*ftanh_(cn);
        cnv[e] = cn;
        stg0[(eloc+e)*72 + j] = (f16)hn;
      }
      *(float2*)(C0 + (size_t)j*BATCH + e0) = make_float2(cnv[0], cnv[1]);
    }
    __syncthreads();
    #pragma unroll
    for (int e=0;e<2;e++){
      const uint4* sp2 = (const uint4*)(stg0 + (eloc+e)*72);
      #pragma unroll
      for (int q=0;q<8;q++){
        const uint4 v = sp2[q];
        h0[e][q*4+0]=bc16(v.x); h0[e][q*4+1]=bc16(v.y);
        h0[e][q*4+2]=bc16(v.z); h0[e][q*4+3]=bc16(v.w);
      }
    }

    // ===== layer 1 (cat [h0_new; h1], weights streamed from L2) =====
    for (int jj = 0; jj < 8; ++jj) {
      const int j = s*8 + jj;
      const float2 cp = *(const float2*)(C1 + (size_t)j*BATCH + e0);
      const float4 bz = *(const float4*)(lb1 + (jj*8+s)*4);
      float z[4][2];
      #pragma unroll
      for (int e=0;e<2;e++){ z[0][e]=bz.x; z[1][e]=bz.y; z[2][e]=bz.z; z[3][e]=bz.w; }
      const uint4* wp = gw1 + jj*512 + s;
      #pragma unroll
      for (int kk = 0; kk < 64; ++kk) {
        const uint4 wq = wp[kk*8];
        const h2_t a0 = (kk<32) ? h0[0][kk] : h1[0][kk-32];
        const h2_t a1 = (kk<32) ? h0[1][kk] : h1[1][kk-32];
        z[0][0]=fdot2(bc16(wq.x),a0,z[0][0]); z[0][1]=fdot2(bc16(wq.x),a1,z[0][1]);
        z[1][0]=fdot2(bc16(wq.y),a0,z[1][0]); z[1][1]=fdot2(bc16(wq.y),a1,z[1][1]);
        z[2][0]=fdot2(bc16(wq.z),a0,z[2][0]); z[2][1]=fdot2(bc16(wq.z),a1,z[2][1]);
        z[3][0]=fdot2(bc16(wq.w),a0,z[3][0]); z[3][1]=fdot2(bc16(wq.w),a1,z[3][1]);
      }
      const float cold[2] = {cp.x, cp.y};
      float cnv[2];
      #pragma unroll
      for (int e=0;e<2;e++){
        const float ig = fsig(z[0][e]);
        const float fg = fsig(z[1][e]);
        const float gg = ftanh_(z[2][e]);
        const float og = fsig(z[3][e]);
        const float cn = fg*cold[e] + ig*gg;
        const float hn = og*ftanh_(cn);
        cnv[e] = cn;
        stg1[(eloc+e)*72 + j] = (f16)hn;
      }
      *(float2*)(C1 + (size_t)j*BATCH + e0) = make_float2(cnv[0], cnv[1]);
    }
    __syncthreads();
    #pragma unroll
    for (int e=0;e<2;e++){
      const uint4* sp2 = (const uint4*)(stg1 + (eloc+e)*72);
      #pragma unroll
      for (int q=0;q<8;q++){
        const uint4 v = sp2[q];
        h1[e][q*4+0]=bc16(v.x); h1[e][q*4+1]=bc16(v.y);
        h1[e][q*4+2]=bc16(v.z); h1[e][q*4+3]=bc16(v.w);
      }
    }
  }

  // ===== decoder =====
  __syncthreads();
  {
    const uint4* sp3 = (const uint4*)(ws + OFF_WD);
    uint4* d = (uint4*)lw0;
    #pragma unroll
    for (int i=0;i<8;i++) d[tid + 256*i] = sp3[tid + 256*i];
    if (tid < 128) ((uint4*)lih)[tid] = ((const uint4*)(ws + OFF_IHD))[tid];
  }
  __syncthreads();

  float xd0[2], xd1[2];
  #pragma unroll
  for (int e=0;e<2;e++){
    const float2 xv = *(const float2*)(obs + ((size_t)(e0+e)*TOBS + (TOBS-1))*2);
    xd0[e]=xv.x; xd1[e]=xv.y;
  }
  const h2_t* low2 = (const h2_t*)lowv;

  for (int p = 0; p < TPRED; ++p) {
    for (int jj = 0; jj < 8; ++jj) {
      const int j = s*8 + jj;
      const float2 cp  = *(const float2*)(C1 + (size_t)j*BATCH + e0);
      const float4 bz  = *(const float4*)(lbd + (jj*8+s)*4);
      const float4 wxa = *(const float4*)(lih + (jj*8+s)*8);
      const float4 wxb = *(const float4*)(lih + (jj*8+s)*8 + 4);
      float z[4][2];
      #pragma unroll
      for (int e=0;e<2;e++){
        z[0][e] = bz.x + wxa.x*xd0[e] + wxa.y*xd1[e];
        z[1][e] = bz.y + wxa.z*xd0[e] + wxa.w*xd1[e];
        z[2][e] = bz.z + wxb.x*xd0[e] + wxb.y*xd1[e];
        z[3][e] = bz.w + wxb.z*xd0[e] + wxb.w*xd1[e];
      }
      const uint4* wp = (const uint4*)lw0 + jj*256 + s;
      #pragma unroll
      for (int kk = 0; kk < 32; ++kk) {
        const uint4 wq = wp[kk*8];
        #pragma unroll
        for (int e=0;e<2;e++){
          z[0][e] = fdot2(bc16(wq.x), h1[e][kk], z[0][e]);
          z[1][e] = fdot2(bc16(wq.y), h1[e][kk], z[1][e]);
          z[2][e] = fdot2(bc16(wq.z), h1[e][kk], z[2][e]);
          z[3][e] = fdot2(bc16(wq.w), h1[e][kk], z[3][e]);
        }
      }
      const float cold[2] = {cp.x, cp.y};
      float cnv[2];
      #pragma unroll
      for (int e=0;e<2;e++){
        const float ig = fsig(z[0][e]);
        const float fg = fsig(z[1][e]);
        const float gg = ftanh_(z[2][e]);
        const float og = fsig(z[3][e]);
        const float cn = fg*cold[e] + ig*gg;
        const float hn = og*ftanh_(cn);
        cnv[e] = cn;
        stg1[(eloc+e)*72 + j] = (f16)hn;
      }
      *(float2*)(C1 + (size_t)j*BATCH + e0) = make_float2(cnv[0], cnv[1]);
    }
    __syncthreads();
    #pragma unroll
    for (int e=0;e<2;e++){
      const uint4* sp2 = (const uint4*)(stg1 + (eloc+e)*72);
      #pragma unroll
      for (int q=0;q<8;q++){
        const uint4 v = sp2[q];
        h1[e][q*4+0]=bc16(v.x); h1[e][q*4+1]=bc16(v.y);
        h1[e][q*4+2]=bc16(v.z); h1[e][q*4+3]=bc16(v.w);
      }
    }
    #pragma unroll
    for (int e=0;e<2;e++){
      float a = lob[0], b2 = lob[1];
      #pragma unroll
      for (int kk=0;kk<32;kk++){
        a  = fdot2(low2[kk],    h1[e][kk], a);
        b2 = fdot2(low2[32+kk], h1[e][kk], b2);
      }
      if (s == 0) *(float2*)(out + ((size_t)(e0+e)*TPRED + p)*2) = make_float2(a, b2);
      xd0[e]=a; xd1[e]=b2;
    }
  }
}

// ---------------- naive fp32 fallback (only if ws too small) ----------------
__global__ void lstm_naive(const float* __restrict__ obs,
    const float* wih0, const float* whh0, const float* bih0, const float* bhh0,
    const float* wih1, const float* whh1, const float* bih1, const float* bhh1,
    const float* dwih, const float* dwhh, const float* dbih, const float* dbhh,
    const float* outw, const float* outb, float* __restrict__ out)
{
  const int b = blockIdx.x*blockDim.x + threadIdx.x;
  if (b >= BATCH) return;
  float h0[64], c0[64], h1[64], c1[64], t0[64], t1[64];
  for (int j=0;j<64;j++){ h0[j]=0.f; c0[j]=0.f; h1[j]=0.f; c1[j]=0.f; }
  for (int t=0;t<TOBS;t++){
    const float x0 = obs[((size_t)b*TOBS+t)*2], x1 = obs[((size_t)b*TOBS+t)*2+1];
    for (int j=0;j<64;j++){
      float zz[4];
      for (int g=0;g<4;g++){
        const int r = g*64+j;
        float acc = bih0[r]+bhh0[r] + wih0[r*2]*x0 + wih0[r*2+1]*x1;
        for (int k=0;k<64;k++) acc += whh0[r*64+k]*h0[k];
        zz[g]=acc;
      }
      const float ig=1.f/(1.f+expf(-zz[0])), fg=1.f/(1.f+expf(-zz[1]));
      const float gg=tanhf(zz[2]), og=1.f/(1.f+expf(-zz[3]));
      c0[j]=fg*c0[j]+ig*gg; t0[j]=og*tanhf(c0[j]);
    }
    for (int j=0;j<64;j++){
      float zz[4];
      for (int g=0;g<4;g++){
        const int r = g*64+j;
        float acc = bih1[r]+bhh1[r];
        for (int k=0;k<64;k++) acc += wih1[r*64+k]*t0[k] + whh1[r*64+k]*h1[k];
        zz[g]=acc;
      }
      const float ig=1.f/(1.f+expf(-zz[0])), fg=1.f/(1.f+expf(-zz[1]));
      const float gg=tanhf(zz[2]), og=1.f/(1.f+expf(-zz[3]));
      c1[j]=fg*c1[j]+ig*gg; t1[j]=og*tanhf(c1[j]);
    }
    for (int j=0;j<64;j++){ h0[j]=t0[j]; h1[j]=t1[j]; }
  }
  float x0 = obs[((size_t)b*TOBS+19)*2], x1 = obs[((size_t)b*TOBS+19)*2+1];
  for (int p=0;p<TPRED;p++){
    for (int j=0;j<64;j++){
      float zz[4];
      for (int g=0;g<4;g++){
        const int r = g*64+j;
        float acc = dbih[r]+dbhh[r] + dwih[r*2]*x0 + dwih[r*2+1]*x1;
        for (int k=0;k<64;k++) acc += dwhh[r*64+k]*h1[k];
        zz[g]=acc;
      }
      const float ig=1.f/(1.f+expf(-zz[0])), fg=1.f/(1.f+expf(-zz[1]));
      const float gg=tanhf(zz[2]), og=1.f/(1.f+expf(-zz[3]));
      c1[j]=fg*c1[j]+ig*gg; t1[j]=og*tanhf(c1[j]);
    }
    for (int j=0;j<64;j++) h1[j]=t1[j];
    float o0=outb[0], o1=outb[1];
    for (int k=0;k<64;k++){ o0+=outw[k]*h1[k]; o1+=outw[64+k]*h1[k]; }
    out[((size_t)b*TPRED+p)*2]=o0; out[((size_t)b*TPRED+p)*2+1]=o1;
    x0=o0; x1=o1;
  }
}

extern "C" void kernel_launch(void* const* d_in, const int* in_sizes, int n_in,
                              void* d_out, int out_size, void* d_ws, size_t ws_size,
                              hipStream_t stream)
{
  const float* obs  = (const float*)d_in[0];
  const float* wih0 = (const float*)d_in[1];
  const float* whh0 = (const float*)d_in[2];
  const float* bih0 = (const float*)d_in[3];
  const float* bhh0 = (const float*)d_in[4];
  const float* wih1 = (const float*)d_in[5];
  const float* whh1 = (const float*)d_in[6];
  const float* bih1 = (const float*)d_in[7];
  const float* bhh1 = (const float*)d_in[8];
  const float* dwih = (const float*)d_in[9];
  const float* dwhh = (const float*)d_in[10];
  const float* dbih = (const float*)d_in[11];
  const float* dbhh = (const float*)d_in[12];
  const float* outw = (const float*)d_in[13];
  const float* outb = (const float*)d_in[14];
  float* outp = (float*)d_out;

  if (ws_size >= WS_NEED) {
    char* ws = (char*)d_ws;
    prep_pack<<<64, 256, 0, stream>>>(wih0, whh0, bih0, bhh0, wih1, whh1, bih1, bhh1,
                                      dwih, dwhh, dbih, dbhh, outw, outb, ws);
    hipMemsetAsync(ws + OFF_C0, 0, (size_t)(16u<<20), stream);
    lstm_fused<<<512, 256, 0, stream>>>(obs, ws, outp);
  } else {
    lstm_naive<<<(BATCH+255)/256, 256, 0, stream>>>(obs, wih0, whh0, bih0, bhh0,
        wih1, whh1, bih1, bhh1, dwih, dwhh, dbih, dbhh, outw, outb, outp);
  }
}

// Round 3
// 953.337 us; speedup vs baseline: 1.9606x; 1.9606x over previous
//
#include <hip/hip_runtime.h>
#include <math.h>

#define BATCH 32768
#define TOBS  20
#define TPRED 12

typedef _Float16 f16;
typedef f16  half8 __attribute__((ext_vector_type(8)));
typedef f16  half4 __attribute__((ext_vector_type(4)));
typedef float f32x4 __attribute__((ext_vector_type(4)));

// ---------------- d_ws layout (bytes) ----------------
// All weight matrices pre-packed in MFMA A-fragment order:
//   frag f16 index = ((rt*KT + kt)*64 + lane)*8 + i
//   element       = W[rt*16 + (lane&15)][kt*32 + (lane>>4)*8 + i]
#define OFF_W0A  0u        // L0:  [Whh0 kt0,1 | aug-compact]  32768 + 4096 = 36864 B
#define OFF_WDA  36864u    // dec: same structure              36864 B
#define OFF_W1   73728u    // L1 cat [Wih1|Whh1], KT=4         65536 B
#define OFF_B1   139264u   // bias1 (bih1+bhh1) f32[256]       1024 B
#define OFF_OUT  140288u   // out-proj frags KT=3 (1 row-tile) 3072 B
#define WS_NEED  ((size_t)143360)

__device__ __forceinline__ float frcp(float x){
#if __has_builtin(__builtin_amdgcn_rcpf)
  return __builtin_amdgcn_rcpf(x);
#else
  return 1.0f/x;
#endif
}
__device__ __forceinline__ float fsig(float x){ return frcp(1.0f + __expf(-x)); }
__device__ __forceinline__ float ftanh_(float x){
  float e = __expf(-2.0f*x); return (1.0f - e)*frcp(1.0f + e);
}
__device__ __forceinline__ f32x4 MFMA(half8 a, half8 b, f32x4 c){
  return __builtin_amdgcn_mfma_f32_16x16x32_f16(a, b, c, 0, 0, 0);
}

// ---------------- weight packing ----------------
__global__ void prep_pack(const float* __restrict__ wih0, const float* __restrict__ whh0,
                          const float* __restrict__ bih0, const float* __restrict__ bhh0,
                          const float* __restrict__ wih1, const float* __restrict__ whh1,
                          const float* __restrict__ bih1, const float* __restrict__ bhh1,
                          const float* __restrict__ dwih, const float* __restrict__ dwhh,
                          const float* __restrict__ dbih, const float* __restrict__ dbhh,
                          const float* __restrict__ outw, const float* __restrict__ outb,
                          char* __restrict__ ws)
{
  const int tid = blockIdx.x*blockDim.x + threadIdx.x;
  const int stride = gridDim.x*blockDim.x;

  f16* w0 = (f16*)(ws + OFF_W0A);
  f16* wd = (f16*)(ws + OFF_WDA);
  // hh frags (kt=0,1): idx -> i, lane, kt, rt
  for (int idx = tid; idx < 16384; idx += stride) {
    int i = idx & 7, lane = (idx>>3)&63, kt = (idx>>9)&1, rt = idx>>10;
    int row = rt*16 + (lane&15);
    int k   = kt*32 + (lane>>4)*8 + i;
    w0[idx] = (f16)whh0[row*64 + k];
    wd[idx] = (f16)dwhh[row*64 + k];
  }
  // aug-compact (quad0 data only): [rt][m][8]: i=0->wih[:,0], 1->wih[:,1], 2->bias
  for (int idx = tid; idx < 2048; idx += stride) {
    int i = idx & 7, m = (idx>>3)&15, rt = idx>>7;
    int row = rt*16 + m;
    float v0 = (i==0) ? wih0[row*2] : (i==1) ? wih0[row*2+1] : (i==2) ? (bih0[row]+bhh0[row]) : 0.f;
    float vd = (i==0) ? dwih[row*2] : (i==1) ? dwih[row*2+1] : (i==2) ? (dbih[row]+dbhh[row]) : 0.f;
    w0[16384 + idx] = (f16)v0;
    wd[16384 + idx] = (f16)vd;
  }
  // L1 cat pack, KT=4: k<64 -> Wih1, else Whh1
  f16* w1 = (f16*)(ws + OFF_W1);
  for (int idx = tid; idx < 32768; idx += stride) {
    int i = idx & 7, lane = (idx>>3)&63, kt = (idx>>9)&3, rt = idx>>11;
    int row = rt*16 + (lane&15);
    int k   = kt*32 + (lane>>4)*8 + i;
    w1[idx] = (f16)((k < 64) ? wih1[row*64 + k] : whh1[row*64 + (k-64)]);
  }
  float* b1 = (float*)(ws + OFF_B1);
  for (int r = tid; r < 256; r += stride) b1[r] = bih1[r] + bhh1[r];
  // out-proj frags KT=3, rows 0,1 real, k=64 -> out_b, else 0
  f16* wo = (f16*)(ws + OFF_OUT);
  for (int idx = tid; idx < 1536; idx += stride) {
    int i = idx & 7, lane = (idx>>3)&63, kt = idx>>9;
    int m = lane&15;
    int k = kt*32 + (lane>>4)*8 + i;
    float v = 0.f;
    if (m < 2) {
      if (k < 64) v = outw[m*64 + k];
      else if (k == 64) v = outb[m];
    }
    wo[idx] = (f16)v;
  }
}

// ---------------- fused MFMA LSTM ----------------
// block = 256 thr (4 waves), wave owns 16 batch elements. grid = 512.
// Per-wave-private LDS h-stages in B-frag order -> no barriers in the loop.
// c-state in VGPRs. D-layout: row=(lane>>4)*4+reg, col=lane&15.
__global__ __launch_bounds__(256, 2)
void lstm_mfma(const float* __restrict__ obs, char* __restrict__ ws, float* __restrict__ out)
{
  __shared__ __align__(16) f16   lw[18432];        // 36 KB: L0 (then dec) hh+aug pack
  __shared__ __align__(16) float lb1[256];         // 1 KB
  __shared__ __align__(16) f16   lout[1536];       // 3 KB
  __shared__ __align__(16) f16   stg[4][2][1024];  // 16 KB: per-wave h0,h1 stages (B-frag order)

  const int tid  = threadIdx.x;
  const int wv   = tid >> 6;
  const int lane = tid & 63;
  const int n    = lane & 15;
  const int quad = lane >> 4;
  const int e0   = blockIdx.x*64 + wv*16;
  const size_t bn = (size_t)(e0 + n);

  // ---- stage weights to LDS ----
  {
    uint4* d = (uint4*)lw;
    const uint4* s = (const uint4*)(ws + OFF_W0A);
    #pragma unroll
    for (int i = 0; i < 9; ++i) d[tid + 256*i] = s[tid + 256*i];
    if (tid < 64)  ((uint4*)lb1)[tid] = ((const uint4*)(ws + OFF_B1))[tid];
    if (tid < 192) ((uint4*)lout)[tid] = ((const uint4*)(ws + OFF_OUT))[tid];
    // zero own-wave stages: stg[wv] = 2048 f16 = 4096 B = 256 uint4 per wave
    uint4 z = {0,0,0,0};
    ((uint4*)&stg[wv][0][0])[lane]       = z;
    ((uint4*)&stg[wv][0][0])[lane + 64]  = z;
    ((uint4*)&stg[wv][0][0])[lane + 128] = z;
    ((uint4*)&stg[wv][0][0])[lane + 192] = z;
  }
  __syncthreads();

  const half8* AW  = (const half8*)lw;          // hh frags: [(rt*2+kt)*64 + lane]
  const half8* AWX = (const half8*)(lw + 16384);// aug-compact: [rt*16 + n] (broadcast over quad)
  const half8* GA  = (const half8*)(ws + OFF_W1);
  const half8* LO  = (const half8*)lout;
  f16* s0 = &stg[wv][0][0];
  f16* s1 = &stg[wv][1][0];

  float c0[16], c1[16];
  #pragma unroll
  for (int q = 0; q < 16; ++q) { c0[q] = 0.f; c1[q] = 0.f; }

  // h-stage store address (f16 units): producer lane holds rows j=jt*16+quad*4+{0..3}
  int staddr[4];
  #pragma unroll
  for (int jt = 0; jt < 4; ++jt)
    staddr[jt] = (jt>>1)*512 + (n + 16*(((jt&1)<<1) + (quad>>1)))*8 + ((quad&1)<<2);

  for (int t = 0; t < TOBS; ++t) {
    const float2 xv = *(const float2*)(obs + (bn*TOBS + t)*2);
    half8 bx = (half8)(f16)0;
    if (quad == 0) { bx[0] = (f16)xv.x; bx[1] = (f16)xv.y; bx[2] = (f16)1.0f; }

    // ===== layer 0: z = Whh0*h0 + [Wih0|b0]*[x;1] =====
    f32x4 acc[16];
    const half8 h0b0 = *(const half8*)(s0 + lane*8);
    const half8 h0b1 = *(const half8*)(s0 + 512 + lane*8);
    #pragma unroll
    for (int rt = 0; rt < 16; ++rt) {
      f32x4 a = {0.f,0.f,0.f,0.f};
      a = MFMA(AW[(rt*2+0)*64 + lane], h0b0, a);
      a = MFMA(AW[(rt*2+1)*64 + lane], h0b1, a);
      a = MFMA(AWX[rt*16 + n],          bx,   a);
      acc[rt] = a;
    }
    #pragma unroll
    for (int jt = 0; jt < 4; ++jt) {
      half4 hh;
      #pragma unroll
      for (int r = 0; r < 4; ++r) {
        const float ig = fsig(acc[jt][r]);
        const float fg = fsig(acc[4+jt][r]);
        const float gg = ftanh_(acc[8+jt][r]);
        const float og = fsig(acc[12+jt][r]);
        const float cn = fg*c0[jt*4+r] + ig*gg;
        c0[jt*4+r] = cn;
        hh[r] = (f16)(og*ftanh_(cn));
      }
      *(half4*)(s0 + staddr[jt]) = hh;
    }

    // ===== layer 1: z = [Wih1|Whh1]*[h0_new; h1] + b1 (A streamed from L2) =====
    const half8 g0 = *(const half8*)(s0 + lane*8);
    const half8 g1 = *(const half8*)(s0 + 512 + lane*8);
    const half8 g2 = *(const half8*)(s1 + lane*8);
    const half8 g3 = *(const half8*)(s1 + 512 + lane*8);
    #pragma unroll
    for (int rt = 0; rt < 16; ++rt) {
      f32x4 a = *(const f32x4*)(lb1 + rt*16 + quad*4);
      a = MFMA(GA[(rt*4+0)*64 + lane], g0, a);
      a = MFMA(GA[(rt*4+1)*64 + lane], g1, a);
      a = MFMA(GA[(rt*4+2)*64 + lane], g2, a);
      a = MFMA(GA[(rt*4+3)*64 + lane], g3, a);
      acc[rt] = a;
    }
    #pragma unroll
    for (int jt = 0; jt < 4; ++jt) {
      half4 hh;
      #pragma unroll
      for (int r = 0; r < 4; ++r) {
        const float ig = fsig(acc[jt][r]);
        const float fg = fsig(acc[4+jt][r]);
        const float gg = ftanh_(acc[8+jt][r]);
        const float og = fsig(acc[12+jt][r]);
        const float cn = fg*c1[jt*4+r] + ig*gg;
        c1[jt*4+r] = cn;
        hh[r] = (f16)(og*ftanh_(cn));
      }
      *(half4*)(s1 + staddr[jt]) = hh;
    }
  }

  // ---- swap in decoder weights ----
  __syncthreads();
  {
    uint4* d = (uint4*)lw;
    const uint4* s = (const uint4*)(ws + OFF_WDA);
    #pragma unroll
    for (int i = 0; i < 9; ++i) d[tid + 256*i] = s[tid + 256*i];
  }
  __syncthreads();

  float x0, x1;
  {
    const float2 xv = *(const float2*)(obs + (bn*TOBS + (TOBS-1))*2);
    x0 = xv.x; x1 = xv.y;
  }
  half8 ob1 = (half8)(f16)0;
  if (quad == 0) ob1[0] = (f16)1.0f;   // constant-1 B frag for out_b

  for (int p = 0; p < TPRED; ++p) {
    half8 bx = (half8)(f16)0;
    if (quad == 0) { bx[0] = (f16)x0; bx[1] = (f16)x1; bx[2] = (f16)1.0f; }

    f32x4 acc[16];
    const half8 hb0 = *(const half8*)(s1 + lane*8);
    const half8 hb1 = *(const half8*)(s1 + 512 + lane*8);
    #pragma unroll
    for (int rt = 0; rt < 16; ++rt) {
      f32x4 a = {0.f,0.f,0.f,0.f};
      a = MFMA(AW[(rt*2+0)*64 + lane], hb0, a);
      a = MFMA(AW[(rt*2+1)*64 + lane], hb1, a);
      a = MFMA(AWX[rt*16 + n],          bx,  a);
      acc[rt] = a;
    }
    #pragma unroll
    for (int jt = 0; jt < 4; ++jt) {
      half4 hh;
      #pragma unroll
      for (int r = 0; r < 4; ++r) {
        const float ig = fsig(acc[jt][r]);
        const float fg = fsig(acc[4+jt][r]);
        const float gg = ftanh_(acc[8+jt][r]);
        const float og = fsig(acc[12+jt][r]);
        const float cn = fg*c1[jt*4+r] + ig*gg;
        c1[jt*4+r] = cn;
        hh[r] = (f16)(og*ftanh_(cn));
      }
      *(half4*)(s1 + staddr[jt]) = hh;
    }

    // out-proj: o = out_w*h_new + out_b  (rows 0,1 of a 16-row tile)
    const half8 nh0 = *(const half8*)(s1 + lane*8);
    const half8 nh1 = *(const half8*)(s1 + 512 + lane*8);
    f32x4 oa = {0.f,0.f,0.f,0.f};
    oa = MFMA(LO[0*64 + lane], nh0, oa);
    oa = MFMA(LO[1*64 + lane], nh1, oa);
    oa = MFMA(LO[2*64 + lane], ob1, oa);

    if (lane < 16)
      *(float2*)(out + (bn*TPRED + p)*2) = make_float2(oa[0], oa[1]);
    x0 = __shfl(oa[0], lane & 15, 64);
    x1 = __shfl(oa[1], lane & 15, 64);
  }
}

// ---------------- naive fp32 fallback (only if ws too small) ----------------
__global__ void lstm_naive(const float* __restrict__ obs,
    const float* wih0, const float* whh0, const float* bih0, const float* bhh0,
    const float* wih1, const float* whh1, const float* bih1, const float* bhh1,
    const float* dwih, const float* dwhh, const float* dbih, const float* dbhh,
    const float* outw, const float* outb, float* __restrict__ out)
{
  const int b = blockIdx.x*blockDim.x + threadIdx.x;
  if (b >= BATCH) return;
  float h0[64], c0[64], h1[64], c1[64], t0[64], t1[64];
  for (int j=0;j<64;j++){ h0[j]=0.f; c0[j]=0.f; h1[j]=0.f; c1[j]=0.f; }
  for (int t=0;t<TOBS;t++){
    const float x0 = obs[((size_t)b*TOBS+t)*2], x1 = obs[((size_t)b*TOBS+t)*2+1];
    for (int j=0;j<64;j++){
      float zz[4];
      for (int g=0;g<4;g++){
        const int r = g*64+j;
        float acc = bih0[r]+bhh0[r] + wih0[r*2]*x0 + wih0[r*2+1]*x1;
        for (int k=0;k<64;k++) acc += whh0[r*64+k]*h0[k];
        zz[g]=acc;
      }
      const float ig=1.f/(1.f+expf(-zz[0])), fg=1.f/(1.f+expf(-zz[1]));
      const float gg=tanhf(zz[2]), og=1.f/(1.f+expf(-zz[3]));
      c0[j]=fg*c0[j]+ig*gg; t0[j]=og*tanhf(c0[j]);
    }
    for (int j=0;j<64;j++){
      float zz[4];
      for (int g=0;g<4;g++){
        const int r = g*64+j;
        float acc = bih1[r]+bhh1[r];
        for (int k=0;k<64;k++) acc += wih1[r*64+k]*t0[k] + whh1[r*64+k]*h1[k];
        zz[g]=acc;
      }
      const float ig=1.f/(1.f+expf(-zz[0])), fg=1.f/(1.f+expf(-zz[1]));
      const float gg=tanhf(zz[2]), og=1.f/(1.f+expf(-zz[3]));
      c1[j]=fg*c1[j]+ig*gg; t1[j]=og*tanhf(c1[j]);
    }
    for (int j=0;j<64;j++){ h0[j]=t0[j]; h1[j]=t1[j]; }
  }
  float x0 = obs[((size_t)b*TOBS+19)*2], x1 = obs[((size_t)b*TOBS+19)*2+1];
  for (int p=0;p<TPRED;p++){
    for (int j=0;j<64;j++){
      float zz[4];
      for (int g=0;g<4;g++){
        const int r = g*64+j;
        float acc = dbih[r]+dbhh[r] + dwih[r*2]*x0 + dwih[r*2+1]*x1;
        for (int k=0;k<64;k++) acc += dwhh[r*64+k]*h1[k];
        zz[g]=acc;
      }
      const float ig=1.f/(1.f+expf(-zz[0])), fg=1.f/(1.f+expf(-zz[1]));
      const float gg=tanhf(zz[2]), og=1.f/(1.f+expf(-zz[3]));
      c1[j]=fg*c1[j]+ig*gg; t1[j]=og*tanhf(c1[j]);
    }
    for (int j=0;j<64;j++) h1[j]=t1[j];
    float o0=outb[0], o1=outb[1];
    for (int k=0;k<64;k++){ o0+=outw[k]*h1[k]; o1+=outw[64+k]*h1[k]; }
    out[((size_t)b*TPRED+p)*2]=o0; out[((size_t)b*TPRED+p)*2+1]=o1;
    x0=o0; x1=o1;
  }
}

extern "C" void kernel_launch(void* const* d_in, const int* in_sizes, int n_in,
                              void* d_out, int out_size, void* d_ws, size_t ws_size,
                              hipStream_t stream)
{
  const float* obs  = (const float*)d_in[0];
  const float* wih0 = (const float*)d_in[1];
  const float* whh0 = (const float*)d_in[2];
  const float* bih0 = (const float*)d_in[3];
  const float* bhh0 = (const float*)d_in[4];
  const float* wih1 = (const float*)d_in[5];
  const float* whh1 = (const float*)d_in[6];
  const float* bih1 = (const float*)d_in[7];
  const float* bhh1 = (const float*)d_in[8];
  const float* dwih = (const float*)d_in[9];
  const float* dwhh = (const float*)d_in[10];
  const float* dbih = (const float*)d_in[11];
  const float* dbhh = (const float*)d_in[12];
  const float* outw = (const float*)d_in[13];
  const float* outb = (const float*)d_in[14];
  float* outp = (float*)d_out;

  if (ws_size >= WS_NEED) {
    char* ws = (char*)d_ws;
    prep_pack<<<64, 256, 0, stream>>>(wih0, whh0, bih0, bhh0, wih1, whh1, bih1, bhh1,
                                      dwih, dwhh, dbih, dbhh, outw, outb, ws);
    lstm_mfma<<<512, 256, 0, stream>>>(obs, ws, outp);
  } else {
    lstm_naive<<<(BATCH+255)/256, 256, 0, stream>>>(obs, wih0, whh0, bih0, bhh0,
        wih1, whh1, bih1, bhh1, dwih, dwhh, dbih, dbhh, outw, outb, outp);
  }
}

// Round 4
// 941.067 us; speedup vs baseline: 1.9862x; 1.0130x over previous
//
#include <hip/hip_runtime.h>
#include <math.h>

#define BATCH 32768
#define TOBS  20
#define TPRED 12

typedef _Float16 f16;
typedef f16  half8 __attribute__((ext_vector_type(8)));
typedef f16  half4 __attribute__((ext_vector_type(4)));
typedef float f32x4 __attribute__((ext_vector_type(4)));

// ---------------- d_ws layout (bytes) ----------------
// All weight matrices pre-packed in MFMA A-fragment order:
//   frag f16 index = ((rt*KT + kt)*64 + lane)*8 + i
//   element       = W[rt*16 + (lane&15)][kt*32 + (lane>>4)*8 + i]
#define OFF_W0A  0u        // L0:  [Whh0 kt0,1 | aug-compact]  32768 + 4096 = 36864 B
#define OFF_WDA  36864u    // dec: same structure              36864 B
#define OFF_W1   73728u    // L1 cat [Wih1|Whh1], KT=4         65536 B
#define OFF_B1   139264u   // bias1 (bih1+bhh1) f32[256]       1024 B
#define OFF_OUT  140288u   // out-proj frags KT=3 (1 row-tile) 3072 B
#define WS_NEED  ((size_t)143360)

__device__ __forceinline__ float frcp(float x){
#if __has_builtin(__builtin_amdgcn_rcpf)
  return __builtin_amdgcn_rcpf(x);
#else
  return 1.0f/x;
#endif
}
__device__ __forceinline__ float fsig(float x){ return frcp(1.0f + __expf(-x)); }
__device__ __forceinline__ float ftanh_(float x){
  float e = __expf(-2.0f*x); return (1.0f - e)*frcp(1.0f + e);
}
__device__ __forceinline__ f32x4 MFMA(half8 a, half8 b, f32x4 c){
  return __builtin_amdgcn_mfma_f32_16x16x32_f16(a, b, c, 0, 0, 0);
}

// ---------------- weight packing ----------------
__global__ void prep_pack(const float* __restrict__ wih0, const float* __restrict__ whh0,
                          const float* __restrict__ bih0, const float* __restrict__ bhh0,
                          const float* __restrict__ wih1, const float* __restrict__ whh1,
                          const float* __restrict__ bih1, const float* __restrict__ bhh1,
                          const float* __restrict__ dwih, const float* __restrict__ dwhh,
                          const float* __restrict__ dbih, const float* __restrict__ dbhh,
                          const float* __restrict__ outw, const float* __restrict__ outb,
                          char* __restrict__ ws)
{
  const int tid = blockIdx.x*blockDim.x + threadIdx.x;
  const int stride = gridDim.x*blockDim.x;

  f16* w0 = (f16*)(ws + OFF_W0A);
  f16* wd = (f16*)(ws + OFF_WDA);
  // hh frags (kt=0,1): idx -> i, lane, kt, rt
  for (int idx = tid; idx < 16384; idx += stride) {
    int i = idx & 7, lane = (idx>>3)&63, kt = (idx>>9)&1, rt = idx>>10;
    int row = rt*16 + (lane&15);
    int k   = kt*32 + (lane>>4)*8 + i;
    w0[idx] = (f16)whh0[row*64 + k];
    wd[idx] = (f16)dwhh[row*64 + k];
  }
  // aug-compact (quad0 data only): [rt][m][8]: i=0->wih[:,0], 1->wih[:,1], 2->bias
  for (int idx = tid; idx < 2048; idx += stride) {
    int i = idx & 7, m = (idx>>3)&15, rt = idx>>7;
    int row = rt*16 + m;
    float v0 = (i==0) ? wih0[row*2] : (i==1) ? wih0[row*2+1] : (i==2) ? (bih0[row]+bhh0[row]) : 0.f;
    float vd = (i==0) ? dwih[row*2] : (i==1) ? dwih[row*2+1] : (i==2) ? (dbih[row]+dbhh[row]) : 0.f;
    w0[16384 + idx] = (f16)v0;
    wd[16384 + idx] = (f16)vd;
  }
  // L1 cat pack, KT=4: k<64 -> Wih1, else Whh1
  f16* w1 = (f16*)(ws + OFF_W1);
  for (int idx = tid; idx < 32768; idx += stride) {
    int i = idx & 7, lane = (idx>>3)&63, kt = (idx>>9)&3, rt = idx>>11;
    int row = rt*16 + (lane&15);
    int k   = kt*32 + (lane>>4)*8 + i;
    w1[idx] = (f16)((k < 64) ? wih1[row*64 + k] : whh1[row*64 + (k-64)]);
  }
  float* b1 = (float*)(ws + OFF_B1);
  for (int r = tid; r < 256; r += stride) b1[r] = bih1[r] + bhh1[r];
  // out-proj frags KT=3, rows 0,1 real, k=64 -> out_b, else 0
  f16* wo = (f16*)(ws + OFF_OUT);
  for (int idx = tid; idx < 1536; idx += stride) {
    int i = idx & 7, lane = (idx>>3)&63, kt = idx>>9;
    int m = lane&15;
    int k = kt*32 + (lane>>4)*8 + i;
    float v = 0.f;
    if (m < 2) {
      if (k < 64) v = outw[m*64 + k];
      else if (k == 64) v = outb[m];
    }
    wo[idx] = (f16)v;
  }
}

// ---------------- fused MFMA LSTM, all weights LDS-resident ----------------
// block = 512 thr (8 waves), 1 block/CU (136 KB LDS), grid = 256.
// Each wave owns 16 batch elements end-to-end; per-wave-private LDS h-stages
// in B-frag order -> no barriers in the recurrence loop. c-state in VGPRs.
// D-layout: row=(lane>>4)*4+reg, col=lane&15.
__global__ __launch_bounds__(512, 2)
void lstm_mfma(const float* __restrict__ obs, char* __restrict__ ws, float* __restrict__ out)
{
  __shared__ __align__(16) f16   lw[18432];        // 36 KB: L0 (then dec) hh+aug pack
  __shared__ __align__(16) f16   lw1[32768];       // 64 KB: L1 cat pack (resident)
  __shared__ __align__(16) float lb1[256];         // 1 KB
  __shared__ __align__(16) f16   lout[1536];       // 3 KB
  __shared__ __align__(16) f16   stg[8][2][1024];  // 32 KB: per-wave h0,h1 stages

  const int tid  = threadIdx.x;
  const int wv   = tid >> 6;
  const int lane = tid & 63;
  const int n    = lane & 15;
  const int quad = lane >> 4;
  const int e0   = blockIdx.x*128 + wv*16;
  const size_t bn = (size_t)(e0 + n);

  // ---- stage weights to LDS ----
  {
    uint4* d = (uint4*)lw;
    const uint4* s = (const uint4*)(ws + OFF_W0A);
    for (int i = tid; i < 2304; i += 512) d[i] = s[i];
    uint4* d1 = (uint4*)lw1;
    const uint4* s1g = (const uint4*)(ws + OFF_W1);
    #pragma unroll
    for (int i = 0; i < 8; ++i) d1[tid + 512*i] = s1g[tid + 512*i];
    if (tid < 64)  ((uint4*)lb1)[tid] = ((const uint4*)(ws + OFF_B1))[tid];
    if (tid < 192) ((uint4*)lout)[tid] = ((const uint4*)(ws + OFF_OUT))[tid];
    // zero own-wave stages: stg[wv] = 2048 f16 = 4096 B = 256 uint4 per wave
    uint4 z = {0,0,0,0};
    ((uint4*)&stg[wv][0][0])[lane]       = z;
    ((uint4*)&stg[wv][0][0])[lane + 64]  = z;
    ((uint4*)&stg[wv][0][0])[lane + 128] = z;
    ((uint4*)&stg[wv][0][0])[lane + 192] = z;
  }
  __syncthreads();

  const half8* AW  = (const half8*)lw;          // hh frags: [(rt*2+kt)*64 + lane]
  const half8* AWX = (const half8*)(lw + 16384);// aug-compact: [rt*16 + n] (broadcast over quad)
  const half8* GA  = (const half8*)lw1;         // L1 cat frags: [(rt*4+kt)*64 + lane]
  const half8* LO  = (const half8*)lout;
  f16* s0 = &stg[wv][0][0];
  f16* s1 = &stg[wv][1][0];

  float c0[16], c1[16];
  #pragma unroll
  for (int q = 0; q < 16; ++q) { c0[q] = 0.f; c1[q] = 0.f; }

  // h-stage store address (f16 units): producer lane holds rows j=jt*16+quad*4+{0..3}
  int staddr[4];
  #pragma unroll
  for (int jt = 0; jt < 4; ++jt)
    staddr[jt] = (jt>>1)*512 + (n + 16*(((jt&1)<<1) + (quad>>1)))*8 + ((quad&1)<<2);

  for (int t = 0; t < TOBS; ++t) {
    const float2 xv = *(const float2*)(obs + (bn*TOBS + t)*2);
    half8 bx = (half8)(f16)0;
    if (quad == 0) { bx[0] = (f16)xv.x; bx[1] = (f16)xv.y; bx[2] = (f16)1.0f; }

    // ===== layer 0: z = Whh0*h0 + [Wih0|b0]*[x;1] =====
    f32x4 acc[16];
    const half8 h0b0 = *(const half8*)(s0 + lane*8);
    const half8 h0b1 = *(const half8*)(s0 + 512 + lane*8);
    #pragma unroll
    for (int rt = 0; rt < 16; ++rt) {
      f32x4 a = {0.f,0.f,0.f,0.f};
      a = MFMA(AW[(rt*2+0)*64 + lane], h0b0, a);
      a = MFMA(AW[(rt*2+1)*64 + lane], h0b1, a);
      a = MFMA(AWX[rt*16 + n],          bx,   a);
      acc[rt] = a;
    }
    #pragma unroll
    for (int jt = 0; jt < 4; ++jt) {
      half4 hh;
      #pragma unroll
      for (int r = 0; r < 4; ++r) {
        const float ig = fsig(acc[jt][r]);
        const float fg = fsig(acc[4+jt][r]);
        const float gg = ftanh_(acc[8+jt][r]);
        const float og = fsig(acc[12+jt][r]);
        const float cn = fg*c0[jt*4+r] + ig*gg;
        c0[jt*4+r] = cn;
        hh[r] = (f16)(og*ftanh_(cn));
      }
      *(half4*)(s0 + staddr[jt]) = hh;
    }

    // ===== layer 1: z = [Wih1|Whh1]*[h0_new; h1] + b1 (A from LDS) =====
    const half8 g0 = *(const half8*)(s0 + lane*8);
    const half8 g1 = *(const half8*)(s0 + 512 + lane*8);
    const half8 g2 = *(const half8*)(s1 + lane*8);
    const half8 g3 = *(const half8*)(s1 + 512 + lane*8);
    #pragma unroll
    for (int rt = 0; rt < 16; ++rt) {
      f32x4 a = *(const f32x4*)(lb1 + rt*16 + quad*4);
      a = MFMA(GA[(rt*4+0)*64 + lane], g0, a);
      a = MFMA(GA[(rt*4+1)*64 + lane], g1, a);
      a = MFMA(GA[(rt*4+2)*64 + lane], g2, a);
      a = MFMA(GA[(rt*4+3)*64 + lane], g3, a);
      acc[rt] = a;
    }
    #pragma unroll
    for (int jt = 0; jt < 4; ++jt) {
      half4 hh;
      #pragma unroll
      for (int r = 0; r < 4; ++r) {
        const float ig = fsig(acc[jt][r]);
        const float fg = fsig(acc[4+jt][r]);
        const float gg = ftanh_(acc[8+jt][r]);
        const float og = fsig(acc[12+jt][r]);
        const float cn = fg*c1[jt*4+r] + ig*gg;
        c1[jt*4+r] = cn;
        hh[r] = (f16)(og*ftanh_(cn));
      }
      *(half4*)(s1 + staddr[jt]) = hh;
    }
  }

  // ---- swap in decoder weights ----
  __syncthreads();
  {
    uint4* d = (uint4*)lw;
    const uint4* s = (const uint4*)(ws + OFF_WDA);
    for (int i = tid; i < 2304; i += 512) d[i] = s[i];
  }
  __syncthreads();

  float x0, x1;
  {
    const float2 xv = *(const float2*)(obs + (bn*TOBS + (TOBS-1))*2);
    x0 = xv.x; x1 = xv.y;
  }
  half8 ob1 = (half8)(f16)0;
  if (quad == 0) ob1[0] = (f16)1.0f;   // constant-1 B frag for out_b

  for (int p = 0; p < TPRED; ++p) {
    half8 bx = (half8)(f16)0;
    if (quad == 0) { bx[0] = (f16)x0; bx[1] = (f16)x1; bx[2] = (f16)1.0f; }

    f32x4 acc[16];
    const half8 hb0 = *(const half8*)(s1 + lane*8);
    const half8 hb1 = *(const half8*)(s1 + 512 + lane*8);
    #pragma unroll
    for (int rt = 0; rt < 16; ++rt) {
      f32x4 a = {0.f,0.f,0.f,0.f};
      a = MFMA(AW[(rt*2+0)*64 + lane], hb0, a);
      a = MFMA(AW[(rt*2+1)*64 + lane], hb1, a);
      a = MFMA(AWX[rt*16 + n],          bx,  a);
      acc[rt] = a;
    }
    #pragma unroll
    for (int jt = 0; jt < 4; ++jt) {
      half4 hh;
      #pragma unroll
      for (int r = 0; r < 4; ++r) {
        const float ig = fsig(acc[jt][r]);
        const float fg = fsig(acc[4+jt][r]);
        const float gg = ftanh_(acc[8+jt][r]);
        const float og = fsig(acc[12+jt][r]);
        const float cn = fg*c1[jt*4+r] + ig*gg;
        c1[jt*4+r] = cn;
        hh[r] = (f16)(og*ftanh_(cn));
      }
      *(half4*)(s1 + staddr[jt]) = hh;
    }

    // out-proj: o = out_w*h_new + out_b  (rows 0,1 of a 16-row tile)
    const half8 nh0 = *(const half8*)(s1 + lane*8);
    const half8 nh1 = *(const half8*)(s1 + 512 + lane*8);
    f32x4 oa = {0.f,0.f,0.f,0.f};
    oa = MFMA(LO[0*64 + lane], nh0, oa);
    oa = MFMA(LO[1*64 + lane], nh1, oa);
    oa = MFMA(LO[2*64 + lane], ob1, oa);

    if (lane < 16)
      *(float2*)(out + (bn*TPRED + p)*2) = make_float2(oa[0], oa[1]);
    x0 = __shfl(oa[0], lane & 15, 64);
    x1 = __shfl(oa[1], lane & 15, 64);
  }
}

// ---------------- naive fp32 fallback (only if ws too small) ----------------
__global__ void lstm_naive(const float* __restrict__ obs,
    const float* wih0, const float* whh0, const float* bih0, const float* bhh0,
    const float* wih1, const float* whh1, const float* bih1, const float* bhh1,
    const float* dwih, const float* dwhh, const float* dbih, const float* dbhh,
    const float* outw, const float* outb, float* __restrict__ out)
{
  const int b = blockIdx.x*blockDim.x + threadIdx.x;
  if (b >= BATCH) return;
  float h0[64], c0[64], h1[64], c1[64], t0[64], t1[64];
  for (int j=0;j<64;j++){ h0[j]=0.f; c0[j]=0.f; h1[j]=0.f; c1[j]=0.f; }
  for (int t=0;t<TOBS;t++){
    const float x0 = obs[((size_t)b*TOBS+t)*2], x1 = obs[((size_t)b*TOBS+t)*2+1];
    for (int j=0;j<64;j++){
      float zz[4];
      for (int g=0;g<4;g++){
        const int r = g*64+j;
        float acc = bih0[r]+bhh0[r] + wih0[r*2]*x0 + wih0[r*2+1]*x1;
        for (int k=0;k<64;k++) acc += whh0[r*64+k]*h0[k];
        zz[g]=acc;
      }
      const float ig=1.f/(1.f+expf(-zz[0])), fg=1.f/(1.f+expf(-zz[1]));
      const float gg=tanhf(zz[2]), og=1.f/(1.f+expf(-zz[3]));
      c0[j]=fg*c0[j]+ig*gg; t0[j]=og*tanhf(c0[j]);
    }
    for (int j=0;j<64;j++){
      float zz[4];
      for (int g=0;g<4;g++){
        const int r = g*64+j;
        float acc = bih1[r]+bhh1[r];
        for (int k=0;k<64;k++) acc += wih1[r*64+k]*t0[k] + whh1[r*64+k]*h1[k];
        zz[g]=acc;
      }
      const float ig=1.f/(1.f+expf(-zz[0])), fg=1.f/(1.f+expf(-zz[1]));
      const float gg=tanhf(zz[2]), og=1.f/(1.f+expf(-zz[3]));
      c1[j]=fg*c1[j]+ig*gg; t1[j]=og*tanhf(c1[j]);
    }
    for (int j=0;j<64;j++){ h0[j]=t0[j]; h1[j]=t1[j]; }
  }
  float x0 = obs[((size_t)b*TOBS+19)*2], x1 = obs[((size_t)b*TOBS+19)*2+1];
  for (int p=0;p<TPRED;p++){
    for (int j=0;j<64;j++){
      float zz[4];
      for (int g=0;g<4;g++){
        const int r = g*64+j;
        float acc = dbih[r]+dbhh[r] + dwih[r*2]*x0 + dwih[r*2+1]*x1;
        for (int k=0;k<64;k++) acc += dwhh[r*64+k]*h1[k];
        zz[g]=acc;
      }
      const float ig=1.f/(1.f+expf(-zz[0])), fg=1.f/(1.f+expf(-zz[1]));
      const float gg=tanhf(zz[2]), og=1.f/(1.f+expf(-zz[3]));
      c1[j]=fg*c1[j]+ig*gg; t1[j]=og*tanhf(c1[j]);
    }
    for (int j=0;j<64;j++) h1[j]=t1[j];
    float o0=outb[0], o1=outb[1];
    for (int k=0;k<64;k++){ o0+=outw[k]*h1[k]; o1+=outw[64+k]*h1[k]; }
    out[((size_t)b*TPRED+p)*2]=o0; out[((size_t)b*TPRED+p)*2+1]=o1;
    x0=o0; x1=o1;
  }
}

extern "C" void kernel_launch(void* const* d_in, const int* in_sizes, int n_in,
                              void* d_out, int out_size, void* d_ws, size_t ws_size,
                              hipStream_t stream)
{
  const float* obs  = (const float*)d_in[0];
  const float* wih0 = (const float*)d_in[1];
  const float* whh0 = (const float*)d_in[2];
  const float* bih0 = (const float*)d_in[3];
  const float* bhh0 = (const float*)d_in[4];
  const float* wih1 = (const float*)d_in[5];
  const float* whh1 = (const float*)d_in[6];
  const float* bih1 = (const float*)d_in[7];
  const float* bhh1 = (const float*)d_in[8];
  const float* dwih = (const float*)d_in[9];
  const float* dwhh = (const float*)d_in[10];
  const float* dbih = (const float*)d_in[11];
  const float* dbhh = (const float*)d_in[12];
  const float* outw = (const float*)d_in[13];
  const float* outb = (const float*)d_in[14];
  float* outp = (float*)d_out;

  if (ws_size >= WS_NEED) {
    char* ws = (char*)d_ws;
    prep_pack<<<64, 256, 0, stream>>>(wih0, whh0, bih0, bhh0, wih1, whh1, bih1, bhh1,
                                      dwih, dwhh, dbih, dbhh, outw, outb, ws);
    lstm_mfma<<<256, 512, 0, stream>>>(obs, ws, outp);
  } else {
    lstm_naive<<<(BATCH+255)/256, 256, 0, stream>>>(obs, wih0, whh0, bih0, bhh0,
        wih1, whh1, bih1, bhh1, dwih, dwhh, dbih, dbhh, outw, outb, outp);
  }
}

// Round 5
// 705.683 us; speedup vs baseline: 2.6486x; 1.3336x over previous
//
#include <hip/hip_runtime.h>
#include <math.h>

#define BATCH 32768
#define TOBS  20
#define TPRED 12

typedef _Float16 f16;
typedef f16  half8 __attribute__((ext_vector_type(8)));
typedef float f32x4 __attribute__((ext_vector_type(4)));

// ---------------- d_ws layout (bytes) ----------------
// Gate-grouped A-fragment packing:
//   packed row r' = rt*16 + m  represents original row (m&3)*64 + rt*4 + (m>>2)
//   (i.e. lane quad Q's 4 accumulator regs = gates i,f,g,o of j = rt*4+Q)
//   frag f16 index = ((rt*KT + kt)*64 + lane)*8 + i
//   element       = W[orig_row(rt, lane&15)][kt*32 + (lane>>4)*8 + i]
#define OFF_W0A  0u        // L0:  [Whh0 kt0,1 | aug-compact]  32768 + 4096 = 36864 B
#define OFF_WDA  36864u    // dec: same structure              36864 B
#define OFF_W1   73728u    // L1 cat [Wih1|Whh1], KT=4         65536 B
#define OFF_B1   139264u   // bias1 gate-grouped f32[256]      1024 B
#define OFF_OUT  140288u   // out-proj frags KT=3 (plain rows) 3072 B
#define WS_NEED  ((size_t)143360)

__device__ __forceinline__ float frcp(float x){
#if __has_builtin(__builtin_amdgcn_rcpf)
  return __builtin_amdgcn_rcpf(x);
#else
  return 1.0f/x;
#endif
}
__device__ __forceinline__ float fsig(float x){ return frcp(1.0f + __expf(-x)); }
__device__ __forceinline__ float ftanh_(float x){
  float e = __expf(-2.0f*x); return (1.0f - e)*frcp(1.0f + e);
}
__device__ __forceinline__ f32x4 MFMA(half8 a, half8 b, f32x4 c){
  return __builtin_amdgcn_mfma_f32_16x16x32_f16(a, b, c, 0, 0, 0);
}
__device__ __forceinline__ int grow(int rt, int m){  // gate-grouped original row
  return (m&3)*64 + rt*4 + (m>>2);
}

// ---------------- weight packing ----------------
__global__ void prep_pack(const float* __restrict__ wih0, const float* __restrict__ whh0,
                          const float* __restrict__ bih0, const float* __restrict__ bhh0,
                          const float* __restrict__ wih1, const float* __restrict__ whh1,
                          const float* __restrict__ bih1, const float* __restrict__ bhh1,
                          const float* __restrict__ dwih, const float* __restrict__ dwhh,
                          const float* __restrict__ dbih, const float* __restrict__ dbhh,
                          const float* __restrict__ outw, const float* __restrict__ outb,
                          char* __restrict__ ws)
{
  const int tid = blockIdx.x*blockDim.x + threadIdx.x;
  const int stride = gridDim.x*blockDim.x;

  f16* w0 = (f16*)(ws + OFF_W0A);
  f16* wd = (f16*)(ws + OFF_WDA);
  // hh frags (kt=0,1)
  for (int idx = tid; idx < 16384; idx += stride) {
    int i = idx & 7, lane = (idx>>3)&63, kt = (idx>>9)&1, rt = idx>>10;
    int row = grow(rt, lane&15);
    int k   = kt*32 + (lane>>4)*8 + i;
    w0[idx] = (f16)whh0[row*64 + k];
    wd[idx] = (f16)dwhh[row*64 + k];
  }
  // aug-compact (quad0 data only): [rt][m][8]: i=0->wih[:,0], 1->wih[:,1], 2->bias
  for (int idx = tid; idx < 2048; idx += stride) {
    int i = idx & 7, m = (idx>>3)&15, rt = idx>>7;
    int row = grow(rt, m);
    float v0 = (i==0) ? wih0[row*2] : (i==1) ? wih0[row*2+1] : (i==2) ? (bih0[row]+bhh0[row]) : 0.f;
    float vd = (i==0) ? dwih[row*2] : (i==1) ? dwih[row*2+1] : (i==2) ? (dbih[row]+dbhh[row]) : 0.f;
    w0[16384 + idx] = (f16)v0;
    wd[16384 + idx] = (f16)vd;
  }
  // L1 cat pack, KT=4: k<64 -> Wih1, else Whh1
  f16* w1 = (f16*)(ws + OFF_W1);
  for (int idx = tid; idx < 32768; idx += stride) {
    int i = idx & 7, lane = (idx>>3)&63, kt = (idx>>9)&3, rt = idx>>11;
    int row = grow(rt, lane&15);
    int k   = kt*32 + (lane>>4)*8 + i;
    w1[idx] = (f16)((k < 64) ? wih1[row*64 + k] : whh1[row*64 + (k-64)]);
  }
  // bias1 gate-grouped: pb1[rt*16+m] = bias[orig_row]
  float* b1 = (float*)(ws + OFF_B1);
  for (int idx = tid; idx < 256; idx += stride) {
    int m = idx & 15, rt = idx >> 4;
    int row = grow(rt, m);
    b1[idx] = bih1[row] + bhh1[row];
  }
  // out-proj frags KT=3 (plain rows 0,1; k=64 -> out_b)
  f16* wo = (f16*)(ws + OFF_OUT);
  for (int idx = tid; idx < 1536; idx += stride) {
    int i = idx & 7, lane = (idx>>3)&63, kt = idx>>9;
    int m = lane&15;
    int k = kt*32 + (lane>>4)*8 + i;
    float v = 0.f;
    if (m < 2) {
      if (k < 64) v = outw[m*64 + k];
      else if (k == 64) v = outb[m];
    }
    wo[idx] = (f16)v;
  }
}

// ---------------- fused MFMA LSTM, gate-grouped tiles ----------------
// block = 512 thr (8 waves), 1 block/CU (~145 KB LDS), grid = 256.
// Wave owns 16 batch cols end-to-end. Per-rt 16x16 D-tile = 4 gates x 4 j's:
// lane (quad,n) gets f32x4 = (i,f,g,o) of j = rt*4+quad, col n -> tiny live set.
// Per-wave-private LDS h-stages [n][72] f16 -> no barriers in recurrence.
__global__ __launch_bounds__(512, 2)
void lstm_mfma(const float* __restrict__ obs, char* __restrict__ ws, float* __restrict__ out)
{
  __shared__ __align__(16) f16   lw[18432];        // 36 KB: L0 (then dec) hh+aug pack
  __shared__ __align__(16) f16   lw1[32768];       // 64 KB: L1 cat pack
  __shared__ __align__(16) float lb1[256];         // 1 KB (gate-grouped)
  __shared__ __align__(16) f16   lout[1536];       // 3 KB
  __shared__ __align__(16) f16   stg[8][2][1280];  // 40 KB: per-wave h0,h1 stages [n][72]

  const int tid  = threadIdx.x;
  const int wv   = tid >> 6;
  const int lane = tid & 63;
  const int n    = lane & 15;
  const int quad = lane >> 4;
  const int e0   = blockIdx.x*128 + wv*16;
  const size_t bn = (size_t)(e0 + n);

  // ---- stage weights to LDS ----
  {
    uint4* d = (uint4*)lw;
    const uint4* s = (const uint4*)(ws + OFF_W0A);
    for (int i = tid; i < 2304; i += 512) d[i] = s[i];
    uint4* d1 = (uint4*)lw1;
    const uint4* s1g = (const uint4*)(ws + OFF_W1);
    #pragma unroll
    for (int i = 0; i < 8; ++i) d1[tid + 512*i] = s1g[tid + 512*i];
    if (tid < 64)  ((uint4*)lb1)[tid] = ((const uint4*)(ws + OFF_B1))[tid];
    if (tid < 192) ((uint4*)lout)[tid] = ((const uint4*)(ws + OFF_OUT))[tid];
    // zero own-wave stages: stg[wv] = 2*1280 f16 = 5120 B = 320 uint4
    uint4 z = {0,0,0,0};
    uint4* zp = (uint4*)&stg[wv][0][0];
    #pragma unroll
    for (int i = 0; i < 5; ++i) zp[lane + 64*i] = z;
  }
  __syncthreads();

  const half8* AW  = (const half8*)lw;          // hh frags: [(rt*2+kt)*64 + lane]
  const half8* AWX = (const half8*)(lw + 16384);// aug-compact: [rt*16 + n]
  const half8* GA  = (const half8*)lw1;         // L1 frags: [(rt*4+kt)*64 + lane]
  const half8* LO  = (const half8*)lout;
  f16* s0 = &stg[wv][0][0];
  f16* s1 = &stg[wv][1][0];

  float c0[16], c1[16];
  #pragma unroll
  for (int q = 0; q < 16; ++q) { c0[q] = 0.f; c1[q] = 0.f; }

  const int brd0 = n*72 + quad*8;        // B-frag read addr (k 0..31)
  const int hwr  = n*72 + quad;          // h write base: + rt*4

  for (int t = 0; t < TOBS; ++t) {
    const float2 xv = *(const float2*)(obs + (bn*TOBS + t)*2);
    half8 bx = (half8)(f16)0;
    if (quad == 0) { bx[0] = (f16)xv.x; bx[1] = (f16)xv.y; bx[2] = (f16)1.0f; }

    // ===== layer 0: z = Whh0*h0 + [Wih0|b0]*[x;1] =====
    {
      const half8 hb0 = *(const half8*)(s0 + brd0);
      const half8 hb1 = *(const half8*)(s0 + brd0 + 32);
      #pragma unroll
      for (int rt = 0; rt < 16; ++rt) {
        f32x4 a = {0.f,0.f,0.f,0.f};
        a = MFMA(AW[(rt*2+0)*64 + lane], hb0, a);
        a = MFMA(AW[(rt*2+1)*64 + lane], hb1, a);
        a = MFMA(AWX[rt*16 + n],          bx,  a);
        const float ig = fsig(a[0]);
        const float fg = fsig(a[1]);
        const float gg = ftanh_(a[2]);
        const float og = fsig(a[3]);
        const float cn = fg*c0[rt] + ig*gg;
        c0[rt] = cn;
        s0[hwr + rt*4] = (f16)(og*ftanh_(cn));
      }
    }

    // ===== layer 1: z = [Wih1|Whh1]*[h0_new; h1] + b1 =====
    {
      const half8 g0 = *(const half8*)(s0 + brd0);
      const half8 g1 = *(const half8*)(s0 + brd0 + 32);
      const half8 g2 = *(const half8*)(s1 + brd0);
      const half8 g3 = *(const half8*)(s1 + brd0 + 32);
      #pragma unroll
      for (int rt = 0; rt < 16; ++rt) {
        f32x4 a = *(const f32x4*)(lb1 + rt*16 + quad*4);
        a = MFMA(GA[(rt*4+0)*64 + lane], g0, a);
        a = MFMA(GA[(rt*4+1)*64 + lane], g1, a);
        a = MFMA(GA[(rt*4+2)*64 + lane], g2, a);
        a = MFMA(GA[(rt*4+3)*64 + lane], g3, a);
        const float ig = fsig(a[0]);
        const float fg = fsig(a[1]);
        const float gg = ftanh_(a[2]);
        const float og = fsig(a[3]);
        const float cn = fg*c1[rt] + ig*gg;
        c1[rt] = cn;
        s1[hwr + rt*4] = (f16)(og*ftanh_(cn));
      }
    }
  }

  // ---- swap in decoder weights ----
  __syncthreads();
  {
    uint4* d = (uint4*)lw;
    const uint4* s = (const uint4*)(ws + OFF_WDA);
    for (int i = tid; i < 2304; i += 512) d[i] = s[i];
  }
  __syncthreads();

  float x0, x1;
  {
    const float2 xv = *(const float2*)(obs + (bn*TOBS + (TOBS-1))*2);
    x0 = xv.x; x1 = xv.y;
  }
  half8 ob1 = (half8)(f16)0;
  if (quad == 0) ob1[0] = (f16)1.0f;   // constant-1 B frag for out_b

  for (int p = 0; p < TPRED; ++p) {
    half8 bx = (half8)(f16)0;
    if (quad == 0) { bx[0] = (f16)x0; bx[1] = (f16)x1; bx[2] = (f16)1.0f; }

    {
      const half8 hb0 = *(const half8*)(s1 + brd0);
      const half8 hb1 = *(const half8*)(s1 + brd0 + 32);
      #pragma unroll
      for (int rt = 0; rt < 16; ++rt) {
        f32x4 a = {0.f,0.f,0.f,0.f};
        a = MFMA(AW[(rt*2+0)*64 + lane], hb0, a);
        a = MFMA(AW[(rt*2+1)*64 + lane], hb1, a);
        a = MFMA(AWX[rt*16 + n],          bx,  a);
        const float ig = fsig(a[0]);
        const float fg = fsig(a[1]);
        const float gg = ftanh_(a[2]);
        const float og = fsig(a[3]);
        const float cn = fg*c1[rt] + ig*gg;
        c1[rt] = cn;
        s1[hwr + rt*4] = (f16)(og*ftanh_(cn));
      }
    }

    // out-proj: o = out_w*h_new + out_b  (rows 0,1 of a 16-row tile)
    const half8 nh0 = *(const half8*)(s1 + brd0);
    const half8 nh1 = *(const half8*)(s1 + brd0 + 32);
    f32x4 oa = {0.f,0.f,0.f,0.f};
    oa = MFMA(LO[0*64 + lane], nh0, oa);
    oa = MFMA(LO[1*64 + lane], nh1, oa);
    oa = MFMA(LO[2*64 + lane], ob1, oa);

    if (lane < 16)
      *(float2*)(out + (bn*TPRED + p)*2) = make_float2(oa[0], oa[1]);
    x0 = __shfl(oa[0], lane & 15, 64);
    x1 = __shfl(oa[1], lane & 15, 64);
  }
}

// ---------------- naive fp32 fallback (only if ws too small) ----------------
__global__ void lstm_naive(const float* __restrict__ obs,
    const float* wih0, const float* whh0, const float* bih0, const float* bhh0,
    const float* wih1, const float* whh1, const float* bih1, const float* bhh1,
    const float* dwih, const float* dwhh, const float* dbih, const float* dbhh,
    const float* outw, const float* outb, float* __restrict__ out)
{
  const int b = blockIdx.x*blockDim.x + threadIdx.x;
  if (b >= BATCH) return;
  float h0[64], c0[64], h1[64], c1[64], t0[64], t1[64];
  for (int j=0;j<64;j++){ h0[j]=0.f; c0[j]=0.f; h1[j]=0.f; c1[j]=0.f; }
  for (int t=0;t<TOBS;t++){
    const float x0 = obs[((size_t)b*TOBS+t)*2], x1 = obs[((size_t)b*TOBS+t)*2+1];
    for (int j=0;j<64;j++){
      float zz[4];
      for (int g=0;g<4;g++){
        const int r = g*64+j;
        float acc = bih0[r]+bhh0[r] + wih0[r*2]*x0 + wih0[r*2+1]*x1;
        for (int k=0;k<64;k++) acc += whh0[r*64+k]*h0[k];
        zz[g]=acc;
      }
      const float ig=1.f/(1.f+expf(-zz[0])), fg=1.f/(1.f+expf(-zz[1]));
      const float gg=tanhf(zz[2]), og=1.f/(1.f+expf(-zz[3]));
      c0[j]=fg*c0[j]+ig*gg; t0[j]=og*tanhf(c0[j]);
    }
    for (int j=0;j<64;j++){
      float zz[4];
      for (int g=0;g<4;g++){
        const int r = g*64+j;
        float acc = bih1[r]+bhh1[r];
        for (int k=0;k<64;k++) acc += wih1[r*64+k]*t0[k] + whh1[r*64+k]*h1[k];
        zz[g]=acc;
      }
      const float ig=1.f/(1.f+expf(-zz[0])), fg=1.f/(1.f+expf(-zz[1]));
      const float gg=tanhf(zz[2]), og=1.f/(1.f+expf(-zz[3]));
      c1[j]=fg*c1[j]+ig*gg; t1[j]=og*tanhf(c1[j]);
    }
    for (int j=0;j<64;j++){ h0[j]=t0[j]; h1[j]=t1[j]; }
  }
  float x0 = obs[((size_t)b*TOBS+19)*2], x1 = obs[((size_t)b*TOBS+19)*2+1];
  for (int p=0;p<TPRED;p++){
    for (int j=0;j<64;j++){
      float zz[4];
      for (int g=0;g<4;g++){
        const int r = g*64+j;
        float acc = dbih[r]+dbhh[r] + dwih[r*2]*x0 + dwih[r*2+1]*x1;
        for (int k=0;k<64;k++) acc += dwhh[r*64+k]*h1[k];
        zz[g]=acc;
      }
      const float ig=1.f/(1.f+expf(-zz[0])), fg=1.f/(1.f+expf(-zz[1]));
      const float gg=tanhf(zz[2]), og=1.f/(1.f+expf(-zz[3]));
      c1[j]=fg*c1[j]+ig*gg; t1[j]=og*tanhf(c1[j]);
    }
    for (int j=0;j<64;j++) h1[j]=t1[j];
    float o0=outb[0], o1=outb[1];
    for (int k=0;k<64;k++){ o0+=outw[k]*h1[k]; o1+=outw[64+k]*h1[k]; }
    out[((size_t)b*TPRED+p)*2]=o0; out[((size_t)b*TPRED+p)*2+1]=o1;
    x0=o0; x1=o1;
  }
}

extern "C" void kernel_launch(void* const* d_in, const int* in_sizes, int n_in,
                              void* d_out, int out_size, void* d_ws, size_t ws_size,
                              hipStream_t stream)
{
  const float* obs  = (const float*)d_in[0];
  const float* wih0 = (const float*)d_in[1];
  const float* whh0 = (const float*)d_in[2];
  const float* bih0 = (const float*)d_in[3];
  const float* bhh0 = (const float*)d_in[4];
  const float* wih1 = (const float*)d_in[5];
  const float* whh1 = (const float*)d_in[6];
  const float* bih1 = (const float*)d_in[7];
  const float* bhh1 = (const float*)d_in[8];
  const float* dwih = (const float*)d_in[9];
  const float* dwhh = (const float*)d_in[10];
  const float* dbih = (const float*)d_in[11];
  const float* dbhh = (const float*)d_in[12];
  const float* outw = (const float*)d_in[13];
  const float* outb = (const float*)d_in[14];
  float* outp = (float*)d_out;

  if (ws_size >= WS_NEED) {
    char* ws = (char*)d_ws;
    prep_pack<<<64, 256, 0, stream>>>(wih0, whh0, bih0, bhh0, wih1, whh1, bih1, bhh1,
                                      dwih, dwhh, dbih, dbhh, outw, outb, ws);
    lstm_mfma<<<256, 512, 0, stream>>>(obs, ws, outp);
  } else {
    lstm_naive<<<(BATCH+255)/256, 256, 0, stream>>>(obs, wih0, whh0, bih0, bhh0,
        wih1, whh1, bih1, bhh1, dwih, dwhh, dbih, dbhh, outw, outb, outp);
  }
}